// Round 7
// baseline (495.867 us; speedup 1.0000x reference)
//
#include <hip/hip_runtime.h>
#include <hip/hip_bf16.h>
#include <cstdint>
#include <cstddef>

typedef __bf16 bf16x8 __attribute__((ext_vector_type(8)));
typedef float  f32x4  __attribute__((ext_vector_type(4)));

__device__ __forceinline__ unsigned short f2bf(float f) {
    __hip_bfloat16 b = __float2bfloat16(f);
    return *reinterpret_cast<unsigned short*>(&b);
}

// fast GELU (tanh form), ~7 VALU ops, saturation-safe
__device__ __forceinline__ float fast_gelu(float x) {
    float x2 = x * x;
    float m  = x * __builtin_fmaf(x2, -0.10294314f, -2.30220795f);
    float e  = __builtin_amdgcn_exp2f(m);
    return x * __builtin_amdgcn_rcpf(1.0f + e);
}

// software grid barrier: all 768 blocks are co-resident (3 blocks/CU enforced
// via __launch_bounds__(256,3); LDS 32KB -> not binding). Device-scope acq_rel
// atomics give cross-XCD L2 writeback/invalidate (G16).
__device__ __forceinline__ void grid_bar(unsigned* ctr, unsigned target) {
    __syncthreads();                       // drains each thread's vmem before barrier
    if (threadIdx.x == 0) {
        __hip_atomic_fetch_add(ctr, 1u, __ATOMIC_ACQ_REL, __HIP_MEMORY_SCOPE_AGENT);
        while (__hip_atomic_load(ctr, __ATOMIC_ACQUIRE, __HIP_MEMORY_SCOPE_AGENT) < target)
            __builtin_amdgcn_s_sleep(1);
    }
    __syncthreads();
}

// ---- R5-proven GEMM tile (NT): BM=BN=128, BK=64, 4 waves x (4x4 of 16x16x32).
// Both operands via global_load_lds (fire-and-forget; R4: VGPR round-trip
// staging regresses 89->146 us). XOR swizzle in 16B chunks: 0 bank conflicts (R2).
template <int EPI, int K, int N>
__device__ __forceinline__ void gemm_tile(const unsigned short* __restrict__ A,
                                          const unsigned short* __restrict__ B,
                                          const float* __restrict__ bias,
                                          void* __restrict__ C,
                                          int bx, int by,
                                          unsigned short* As, unsigned short* Bs) {
    const int tid  = threadIdx.x;
    const int lane = tid & 63;
    const int wid  = tid >> 6;
    const int mBase = (wid >> 1) * 64;
    const int nBase = (wid & 1) * 64;
    const int lr = lane & 15;
    const int lq = lane >> 4;

    const size_t aRow0 = (size_t)by * 128;
    const size_t bRow0 = (size_t)bx * 128;

    const int rA  = tid >> 3;
    const int cSw = (((tid & 7) ^ (rA & 7)) << 3);
    const unsigned short* ga = A + (aRow0 + rA) * (size_t)K + cSw;
    const unsigned short* gb = B + (bRow0 + rA) * (size_t)K + cSw;
    unsigned short* ldsA = As + tid * 8;
    unsigned short* ldsB = Bs + tid * 8;

    f32x4 acc[4][4];
    #pragma unroll
    for (int i = 0; i < 4; ++i)
        #pragma unroll
        for (int j = 0; j < 4; ++j)
            acc[i][j] = f32x4{0.f, 0.f, 0.f, 0.f};

    const int swz0 = ((lq ^ (lr & 7)) << 3);
    const int swz1 = (((4 + lq) ^ (lr & 7)) << 3);

    #pragma unroll 2
    for (int k0 = 0; k0 < K; k0 += 64) {
        __syncthreads();
        #pragma unroll
        for (int t = 0; t < 4; ++t) {
            __builtin_amdgcn_global_load_lds(
                (const __attribute__((address_space(1))) void*)(ga + (size_t)t * 32 * K),
                (__attribute__((address_space(3))) void*)(ldsA + t * 2048), 16, 0, 0);
            __builtin_amdgcn_global_load_lds(
                (const __attribute__((address_space(1))) void*)(gb + (size_t)t * 32 * K),
                (__attribute__((address_space(3))) void*)(ldsB + t * 2048), 16, 0, 0);
        }
        ga += 64;
        gb += 64;
        __syncthreads();
        #pragma unroll
        for (int ks = 0; ks < 2; ++ks) {
            const int swz = ks ? swz1 : swz0;
            bf16x8 avec[4], bvec[4];
            #pragma unroll
            for (int i = 0; i < 4; ++i) {
                avec[i] = *(const bf16x8*)&As[(mBase + i * 16 + lr) * 64 + swz];
                bvec[i] = *(const bf16x8*)&Bs[(nBase + i * 16 + lr) * 64 + swz];
            }
            #pragma unroll
            for (int mi = 0; mi < 4; ++mi)
                #pragma unroll
                for (int ni = 0; ni < 4; ++ni)
                    acc[mi][ni] = __builtin_amdgcn_mfma_f32_16x16x32_bf16(
                        avec[mi], bvec[ni], acc[mi][ni], 0, 0, 0);
        }
    }

    // epilogue. C/D layout: col = lane&15, row = (lane>>4)*4 + reg
    #pragma unroll
    for (int mi = 0; mi < 4; ++mi) {
        #pragma unroll
        for (int ni = 0; ni < 4; ++ni) {
            int col = (int)bRow0 + nBase + ni * 16 + lr;
            float bv = bias[col];
            #pragma unroll
            for (int r = 0; r < 4; ++r) {
                size_t row = aRow0 + mBase + mi * 16 + lq * 4 + r;
                float v = acc[mi][ni][r] + bv;
                if (EPI == 0) {
                    ((unsigned short*)C)[row * (size_t)N + col] = f2bf(fast_gelu(v));
                } else {
                    ((float*)C)[row * (size_t)N + col] = v;
                }
            }
        }
    }
}

// ---- one persistent kernel, 768 blocks (3/CU): partials+cvt | tern+cvt | GEMM1 | GEMM2
__global__ __launch_bounds__(256, 3)
void ffn_fused_kernel(const float* __restrict__ x,
                      const float* __restrict__ W1, const float* __restrict__ b1,
                      const float* __restrict__ W2, const float* __restrict__ b2,
                      float* __restrict__ out,
                      unsigned* __restrict__ ctr,      // >= 3 zeroed counters
                      float* __restrict__ part,        // 512 floats
                      unsigned short* __restrict__ W1t,
                      unsigned short* __restrict__ W2t,
                      unsigned short* __restrict__ xb,
                      unsigned short* __restrict__ h) {
    __shared__ __align__(16) unsigned short As[128 * 64];
    __shared__ __align__(16) unsigned short Bs[128 * 64];
    __shared__ float ps[4];
    __shared__ float sscale;

    const int bid = blockIdx.x;
    const int tid = threadIdx.x;
    const int lane = tid & 63, wv = tid >> 6;

    const int N4W = 1 << 20;       // W elems / 4
    const int N4X = 1 << 21;       // x elems / 4
    const int XHALF = 1 << 20;     // cvt split point

    // ---- phase 1: blocks 0..255 |W1| partials, 256..511 |W2|, 512..767 cvt x[0,half)
    {
        int seg = bid >> 8;
        int b = bid & 255;
        if (seg < 2) {
            const float4* w = (const float4*)(seg ? W2 : W1);
            float s = 0.0f;
            for (int i = b * 256 + tid; i < N4W; i += 256 * 256) {
                float4 v = w[i];
                s += fabsf(v.x) + fabsf(v.y) + fabsf(v.z) + fabsf(v.w);
            }
            #pragma unroll
            for (int o = 32; o > 0; o >>= 1) s += __shfl_down(s, o, 64);
            if (lane == 0) ps[wv] = s;
            __syncthreads();
            if (tid == 0) part[bid] = ps[0] + ps[1] + ps[2] + ps[3];
        } else {
            const float4* xf = (const float4*)x;
            ushort4* xo = (ushort4*)xb;
            for (int i = b * 256 + tid; i < XHALF; i += 256 * 256) {
                float4 v = xf[i];
                ushort4 o;
                o.x = f2bf(v.x); o.y = f2bf(v.y); o.z = f2bf(v.z); o.w = f2bf(v.w);
                xo[i] = o;
            }
        }
    }
    grid_bar(&ctr[0], 768u);

    // ---- phase 2: reduce partials -> scale; ternarize (W1: blocks<384, W2: rest);
    //              cvt x[half, end) on all blocks
    {
        int seg = (bid < 384) ? 0 : 1;
        float s = part[seg * 256 + tid];           // 256 partials, tid covers all
        #pragma unroll
        for (int o = 32; o > 0; o >>= 1) s += __shfl_down(s, o, 64);
        __syncthreads();                           // ps reuse
        if (lane == 0) ps[wv] = s;
        __syncthreads();
        if (tid == 0)
            sscale = fmaxf((ps[0] + ps[1] + ps[2] + ps[3]) * (1.0f / 4194304.0f), 1e-8f);
        __syncthreads();
        float inv = 1.0f / sscale;

        int b = seg ? (bid - 384) : bid;           // 0..383
        const float4* w = (const float4*)(seg ? W2 : W1);
        ushort4* t = seg ? (ushort4*)W2t : (ushort4*)W1t;
        for (int i = b * 256 + tid; i < N4W; i += 384 * 256) {
            float4 v = w[i];
            ushort4 o;
            o.x = f2bf(fminf(fmaxf(rintf(v.x * inv), -1.0f), 1.0f));
            o.y = f2bf(fminf(fmaxf(rintf(v.y * inv), -1.0f), 1.0f));
            o.z = f2bf(fminf(fmaxf(rintf(v.z * inv), -1.0f), 1.0f));
            o.w = f2bf(fminf(fmaxf(rintf(v.w * inv), -1.0f), 1.0f));
            t[i] = o;
        }
        const float4* xf = (const float4*)x;
        ushort4* xo = (ushort4*)xb;
        for (int i = XHALF + bid * 256 + tid; i < N4X; i += 768 * 256) {
            float4 v = xf[i];
            ushort4 o;
            o.x = f2bf(v.x); o.y = f2bf(v.y); o.z = f2bf(v.z); o.w = f2bf(v.w);
            xo[i] = o;
        }
    }
    grid_bar(&ctr[1], 768u);

    // ---- phase 3: GEMM1  h = gelu(x*W1t^T + b1); 2048 tiles, stride 768
    //      (768 % 32 == 0 -> fixed bx per block: W1t tile stays L2-hot)
    #pragma unroll 1
    for (int t = bid; t < 2048; t += 768)
        gemm_tile<0, 1024, 4096>(xb, W1t, b1, h, t & 31, t >> 5, As, Bs);
    grid_bar(&ctr[2], 768u);

    // ---- phase 4: GEMM2  out = h*W2t^T + b2; 512 tiles on blocks < 512
    if (bid < 512)
        gemm_tile<1, 4096, 1024>(h, W2t, b2, out, bid & 7, bid >> 3, As, Bs);
}

// ---------------- launch ----------------

extern "C" void kernel_launch(void* const* d_in, const int* in_sizes, int n_in,
                              void* d_out, int out_size, void* d_ws, size_t ws_size,
                              hipStream_t stream) {
    const float* x  = (const float*)d_in[0];   // [4,2048,1024]
    const float* W1 = (const float*)d_in[1];   // [4096,1024]
    const float* b1 = (const float*)d_in[2];   // [4096]
    const float* W2 = (const float*)d_in[3];   // [1024,4096]
    const float* b2 = (const float*)d_in[4];   // [1024]
    float* out = (float*)d_out;                // fp32 [4,2048,1024]

    const size_t nW = 4096ull * 1024ull;       // 4194304
    const size_t nX = 8192ull * 1024ull;       // 8388608

    char* ws = (char*)d_ws;
    unsigned* ctr = (unsigned*)ws;                               // 256 B (zeroed)
    float* part = (float*)(ws + 256);                            // 2 KB
    unsigned short* W1t = (unsigned short*)(ws + 16384);         // 8.39 MB
    unsigned short* W2t = W1t + nW;                              // 8.39 MB
    unsigned short* xb  = W2t + nW;                              // 16.78 MB
    unsigned short* h   = xb + nX;                               // 67.1 MB

    hipMemsetAsync(ctr, 0, 256, stream);       // zero barrier counters (capturable)

    ffn_fused_kernel<<<dim3(768), dim3(256), 0, stream>>>(
        x, W1, b1, W2, b2, out, ctr, part, W1t, W2t, xb, h);
}

// Round 8
// 466.947 us; speedup vs baseline: 1.0619x; 1.0619x over previous
//
#include <hip/hip_runtime.h>
#include <hip/hip_bf16.h>
#include <cstdint>
#include <cstddef>

typedef __bf16 bf16x8 __attribute__((ext_vector_type(8)));
typedef float  f32x4  __attribute__((ext_vector_type(4)));

__device__ __forceinline__ unsigned short f2bf(float f) {
    __hip_bfloat16 b = __float2bfloat16(f);
    return *reinterpret_cast<unsigned short*>(&b);
}

// fast GELU (tanh form), ~7 VALU ops, saturation-safe
__device__ __forceinline__ float fast_gelu(float x) {
    float x2 = x * x;
    float m  = x * __builtin_fmaf(x2, -0.10294314f, -2.30220795f);
    float e  = __builtin_amdgcn_exp2f(m);
    return x * __builtin_amdgcn_rcpf(1.0f + e);
}

// software grid barrier, all 768 blocks co-resident (3/CU via launch_bounds).
// CRITICAL (R7 lesson): spin with RELAXED agent-scope loads — an ACQUIRE poll
// emits buffer_inv (full per-XCD L2 invalidate) EVERY iteration, which turned
// the aux phases into an HBM-latency crawl (421 us total). One acquire fence
// after the loop gives the needed cross-XCD visibility; arrival RELEASE gives
// the L2 writeback.
__device__ __forceinline__ void grid_bar(unsigned* ctr, unsigned target) {
    __syncthreads();                  // all waves drain their stores (vmcnt(0))
    if (threadIdx.x == 0) {
        __hip_atomic_fetch_add(ctr, 1u, __ATOMIC_RELEASE, __HIP_MEMORY_SCOPE_AGENT);
        unsigned v;
        do {
            __builtin_amdgcn_s_sleep(16);
            v = __hip_atomic_load(ctr, __ATOMIC_RELAXED, __HIP_MEMORY_SCOPE_AGENT);
        } while (v < target);
        __builtin_amdgcn_fence(__ATOMIC_ACQUIRE, "agent");   // single L2 inv
    }
    __syncthreads();
}

// ---- R5-proven GEMM tile (NT): BM=BN=128, BK=64, 4 waves x (4x4 of 16x16x32).
// Both operands via global_load_lds (fire-and-forget; R4: VGPR round-trip
// staging regresses 89->146 us). XOR swizzle in 16B chunks: 0 bank conflicts (R2).
template <int EPI, int K, int N>
__device__ __forceinline__ void gemm_tile(const unsigned short* __restrict__ A,
                                          const unsigned short* __restrict__ B,
                                          const float* __restrict__ bias,
                                          void* __restrict__ C,
                                          int bx, int by,
                                          unsigned short* As, unsigned short* Bs) {
    const int tid  = threadIdx.x;
    const int lane = tid & 63;
    const int wid  = tid >> 6;
    const int mBase = (wid >> 1) * 64;
    const int nBase = (wid & 1) * 64;
    const int lr = lane & 15;
    const int lq = lane >> 4;

    const size_t aRow0 = (size_t)by * 128;
    const size_t bRow0 = (size_t)bx * 128;

    const int rA  = tid >> 3;
    const int cSw = (((tid & 7) ^ (rA & 7)) << 3);
    const unsigned short* ga = A + (aRow0 + rA) * (size_t)K + cSw;
    const unsigned short* gb = B + (bRow0 + rA) * (size_t)K + cSw;
    unsigned short* ldsA = As + tid * 8;
    unsigned short* ldsB = Bs + tid * 8;

    f32x4 acc[4][4];
    #pragma unroll
    for (int i = 0; i < 4; ++i)
        #pragma unroll
        for (int j = 0; j < 4; ++j)
            acc[i][j] = f32x4{0.f, 0.f, 0.f, 0.f};

    const int swz0 = ((lq ^ (lr & 7)) << 3);
    const int swz1 = (((4 + lq) ^ (lr & 7)) << 3);

    #pragma unroll 2
    for (int k0 = 0; k0 < K; k0 += 64) {
        __syncthreads();
        #pragma unroll
        for (int t = 0; t < 4; ++t) {
            __builtin_amdgcn_global_load_lds(
                (const __attribute__((address_space(1))) void*)(ga + (size_t)t * 32 * K),
                (__attribute__((address_space(3))) void*)(ldsA + t * 2048), 16, 0, 0);
            __builtin_amdgcn_global_load_lds(
                (const __attribute__((address_space(1))) void*)(gb + (size_t)t * 32 * K),
                (__attribute__((address_space(3))) void*)(ldsB + t * 2048), 16, 0, 0);
        }
        ga += 64;
        gb += 64;
        __syncthreads();
        #pragma unroll
        for (int ks = 0; ks < 2; ++ks) {
            const int swz = ks ? swz1 : swz0;
            bf16x8 avec[4], bvec[4];
            #pragma unroll
            for (int i = 0; i < 4; ++i) {
                avec[i] = *(const bf16x8*)&As[(mBase + i * 16 + lr) * 64 + swz];
                bvec[i] = *(const bf16x8*)&Bs[(nBase + i * 16 + lr) * 64 + swz];
            }
            #pragma unroll
            for (int mi = 0; mi < 4; ++mi)
                #pragma unroll
                for (int ni = 0; ni < 4; ++ni)
                    acc[mi][ni] = __builtin_amdgcn_mfma_f32_16x16x32_bf16(
                        avec[mi], bvec[ni], acc[mi][ni], 0, 0, 0);
        }
    }

    // epilogue. C/D layout: col = lane&15, row = (lane>>4)*4 + reg
    #pragma unroll
    for (int mi = 0; mi < 4; ++mi) {
        #pragma unroll
        for (int ni = 0; ni < 4; ++ni) {
            int col = (int)bRow0 + nBase + ni * 16 + lr;
            float bv = bias[col];
            #pragma unroll
            for (int r = 0; r < 4; ++r) {
                size_t row = aRow0 + mBase + mi * 16 + lq * 4 + r;
                float v = acc[mi][ni][r] + bv;
                if (EPI == 0) {
                    ((unsigned short*)C)[row * (size_t)N + col] = f2bf(fast_gelu(v));
                } else {
                    ((float*)C)[row * (size_t)N + col] = v;
                }
            }
        }
    }
}

// ---- one persistent kernel, 768 blocks (3/CU): partials+cvt | tern | GEMM1 | GEMM2
__global__ __launch_bounds__(256, 3)
void ffn_fused_kernel(const float* __restrict__ x,
                      const float* __restrict__ W1, const float* __restrict__ b1,
                      const float* __restrict__ W2, const float* __restrict__ b2,
                      float* __restrict__ out,
                      unsigned* __restrict__ ctr,      // >= 3 zeroed counters
                      float* __restrict__ part,        // 512 floats
                      unsigned short* __restrict__ W1t,
                      unsigned short* __restrict__ W2t,
                      unsigned short* __restrict__ xb,
                      unsigned short* __restrict__ h) {
    __shared__ __align__(16) unsigned short As[128 * 64];
    __shared__ __align__(16) unsigned short Bs[128 * 64];
    __shared__ float ps[4];
    __shared__ float sscale;

    const int bid = blockIdx.x;
    const int tid = threadIdx.x;
    const int lane = tid & 63, wv = tid >> 6;

    const int N4W = 1 << 20;       // W elems / 4
    const int N4X = 1 << 21;       // x elems / 4

    // ---- phase 1: blocks 0..255 |W1| partials, 256..511 |W2| partials,
    //               512..767 cvt x (full) -> bf16
    {
        int seg = bid >> 8;
        int b = bid & 255;
        if (seg < 2) {
            const float4* w = (const float4*)(seg ? W2 : W1);
            float s = 0.0f;
            for (int i = b * 256 + tid; i < N4W; i += 256 * 256) {
                float4 v = w[i];
                s += fabsf(v.x) + fabsf(v.y) + fabsf(v.z) + fabsf(v.w);
            }
            #pragma unroll
            for (int o = 32; o > 0; o >>= 1) s += __shfl_down(s, o, 64);
            if (lane == 0) ps[wv] = s;
            __syncthreads();
            if (tid == 0) part[bid] = ps[0] + ps[1] + ps[2] + ps[3];
        } else {
            const float4* xf = (const float4*)x;
            ushort4* xo = (ushort4*)xb;
            for (int i = b * 256 + tid; i < N4X; i += 256 * 256) {
                float4 v = xf[i];
                ushort4 o;
                o.x = f2bf(v.x); o.y = f2bf(v.y); o.z = f2bf(v.z); o.w = f2bf(v.w);
                xo[i] = o;
            }
        }
    }
    grid_bar(&ctr[0], 768u);

    // ---- phase 2: reduce partials -> scale; ternarize (W1: blocks<384, W2: rest)
    {
        int seg = (bid < 384) ? 0 : 1;
        float s = part[seg * 256 + tid];           // 256 partials
        #pragma unroll
        for (int o = 32; o > 0; o >>= 1) s += __shfl_down(s, o, 64);
        if (lane == 0) ps[wv] = s;
        __syncthreads();
        if (tid == 0)
            sscale = fmaxf((ps[0] + ps[1] + ps[2] + ps[3]) * (1.0f / 4194304.0f), 1e-8f);
        __syncthreads();
        float inv = 1.0f / sscale;

        int b = seg ? (bid - 384) : bid;           // 0..383
        const float4* w = (const float4*)(seg ? W2 : W1);
        ushort4* t = seg ? (ushort4*)W2t : (ushort4*)W1t;
        for (int i = b * 256 + tid; i < N4W; i += 384 * 256) {
            float4 v = w[i];
            ushort4 o;
            o.x = f2bf(fminf(fmaxf(rintf(v.x * inv), -1.0f), 1.0f));
            o.y = f2bf(fminf(fmaxf(rintf(v.y * inv), -1.0f), 1.0f));
            o.z = f2bf(fminf(fmaxf(rintf(v.z * inv), -1.0f), 1.0f));
            o.w = f2bf(fminf(fmaxf(rintf(v.w * inv), -1.0f), 1.0f));
            t[i] = o;
        }
    }
    grid_bar(&ctr[1], 768u);

    // ---- phase 3: GEMM1  h = gelu(x*W1t^T + b1); 2048 tiles, stride 768
    //      (768 % 32 == 0 -> fixed bx per block: W1t tile stays L2-hot)
    #pragma unroll 1
    for (int t = bid; t < 2048; t += 768)
        gemm_tile<0, 1024, 4096>(xb, W1t, b1, h, t & 31, t >> 5, As, Bs);
    grid_bar(&ctr[2], 768u);

    // ---- phase 4: GEMM2  out = h*W2t^T + b2; 512 tiles on blocks < 512
    if (bid < 512)
        gemm_tile<1, 4096, 1024>(h, W2t, b2, out, bid & 7, bid >> 3, As, Bs);
}

// ---------------- launch ----------------

extern "C" void kernel_launch(void* const* d_in, const int* in_sizes, int n_in,
                              void* d_out, int out_size, void* d_ws, size_t ws_size,
                              hipStream_t stream) {
    const float* x  = (const float*)d_in[0];   // [4,2048,1024]
    const float* W1 = (const float*)d_in[1];   // [4096,1024]
    const float* b1 = (const float*)d_in[2];   // [4096]
    const float* W2 = (const float*)d_in[3];   // [1024,4096]
    const float* b2 = (const float*)d_in[4];   // [1024]
    float* out = (float*)d_out;                // fp32 [4,2048,1024]

    const size_t nW = 4096ull * 1024ull;       // 4194304
    const size_t nX = 8192ull * 1024ull;       // 8388608

    char* ws = (char*)d_ws;
    unsigned* ctr = (unsigned*)ws;                               // 256 B (zeroed)
    float* part = (float*)(ws + 256);                            // 2 KB
    unsigned short* W1t = (unsigned short*)(ws + 16384);         // 8.39 MB
    unsigned short* W2t = W1t + nW;                              // 8.39 MB
    unsigned short* xb  = W2t + nW;                              // 16.78 MB
    unsigned short* h   = xb + nX;                               // 67.1 MB

    hipMemsetAsync(ctr, 0, 256, stream);       // zero barrier counters (capturable)

    ffn_fused_kernel<<<dim3(768), dim3(256), 0, stream>>>(
        x, W1, b1, W2, b2, out, ctr, part, W1t, W2t, xb, h);
}